// Round 8
// baseline (137.689 us; speedup 1.0000x reference)
//
#include <hip/hip_runtime.h>
#include <hip/hip_bf16.h>
#include <math.h>

#define Q 9
#define NPIX (768 * 768)

typedef short bf16x8 __attribute__((ext_vector_type(8)));
typedef float f32x4 __attribute__((ext_vector_type(4)));
typedef int i32x4 __attribute__((ext_vector_type(4)));

// ws layout (shorts):
//   [0,4096)      A1a frags: 8 groups x 512   (W1e, m-half A, feature phiA(m)=8*(m>>2)+(m&3))
//   [4096,8192)   A1b frags: 8 groups x 512   (m-half B, phiB = phiA+4)
//   [8192,12288)  A3 frags:  8 groups x 512   (W3e, rows 0..2 used)
//   [12288,13312) A2a,A2b frags (W2)
// ws floats: b3t at float idx [6656,6659)
#define A1BV 512    // bf16x8-vector indices
#define A3V  1024
#define A2V  1536
#define B3TF 6656

__device__ __forceinline__ unsigned short f2bf(float x) {  // prep only
    unsigned u = __builtin_bit_cast(unsigned, x);
    unsigned r = u + 0x7FFFu + ((u >> 16) & 1u);
    return (unsigned short)(r >> 16);
}

// pack two f32 -> dword of two bf16 via v_cvt_pk_bf16_f32; first arg in LOW half
__device__ __forceinline__ unsigned pk2(float e, float o) {
    __hip_bfloat162 h = __float22bfloat162_rn(make_float2(e, o));
    unsigned u;
    __builtin_memcpy(&u, &h, 4);
    return u;
}

__device__ __forceinline__ bf16x8 mk8(unsigned w0, unsigned w1, unsigned w2, unsigned w3) {
    i32x4 t = {(int)w0, (int)w1, (int)w2, (int)w3};
    return __builtin_bit_cast(bf16x8, t);
}

// ---- prep: pack fused weights into per-lane 16x16x32 A-fragment order ----
// A-frag layout (HW-proven in R2): lane l holds A[m=l&15][k=(l>>4)*8+j], j=0..7.
__global__ void prep_kernel(const float* __restrict__ actions,
                            const float* __restrict__ inv_actions,
                            const float* __restrict__ W1,
                            const float* __restrict__ b1,
                            const float* __restrict__ W2,
                            const float* __restrict__ W3,
                            const float* __restrict__ b3,
                            short* __restrict__ wsb,
                            float* __restrict__ wsf) {
    const int idx = blockIdx.x * 256 + threadIdx.x;
    if (idx < 8192) {
        // A1a / A1b: W1e[g][k][feat]; k<6: sum_i Ainv[g,i,k]*W1[i,feat]; k==6: b1; else 0
        int j = idx & 7, l = (idx >> 3) & 63, g = (idx >> 9) & 7, half = idx >> 12;
        int m = l & 15, quad = l >> 4, k = quad * 8 + j;
        int feat = 8 * (m >> 2) + (m & 3) + 4 * half;
        float v = 0.f;
        if (k < 6) {
            #pragma unroll
            for (int i = 0; i < 6; i++)
                v += inv_actions[g * 81 + i * 9 + k] * W1[i * 32 + feat];
        } else if (k == 6) v = b1[feat];
        wsb[idx] = (short)f2bf(v);
    } else if (idx < 12288) {
        // A3: W3e[g][k][m] = sum_j3 W3[k,j3]*A[g,6+m,6+j3], m<3 else 0
        int t = idx - 8192;
        int j = t & 7, l = (t >> 3) & 63, g = t >> 9;
        int m = l & 15, quad = l >> 4, k = quad * 8 + j;
        float v = 0.f;
        if (m < 3) {
            #pragma unroll
            for (int j3 = 0; j3 < 3; j3++)
                v += W3[k * 3 + j3] * actions[g * 81 + (6 + m) * 9 + (6 + j3)];
        }
        wsb[idx] = (short)f2bf(v);
    } else if (idx < 13312) {
        // A2a / A2b: W2[k][feat]
        int t = idx - 12288;
        int j = t & 7, l = (t >> 3) & 63, half = t >> 9;
        int m = l & 15, quad = l >> 4, k = quad * 8 + j;
        int feat = 8 * (m >> 2) + (m & 3) + 4 * half;
        wsb[idx] = (short)f2bf(W2[k * 32 + feat]);
    } else if (idx < 13315) {
        int t = idx - 13312;
        float acc = 0.f;
        for (int g = 0; g < 8; g++)
            #pragma unroll
            for (int j = 0; j < 3; j++)
                acc += actions[g * 81 + (6 + t) * 9 + (6 + j)] * b3[j];
        wsf[B3TF + t] = acc;
    }
}

__global__ __launch_bounds__(256, 2) void lbm_kernel(
    const float* __restrict__ f,
    const float* __restrict__ Minv,
    const float* __restrict__ w,
    const float* __restrict__ b2,
    const short* __restrict__ wsb,
    const float* __restrict__ wsf,
    float* __restrict__ out) {
    __shared__ float oL[4][64][4];

    const int tid = threadIdx.x;
    const int wv = tid >> 6;
    const int l = tid & 63;
    const int quad = l >> 4;
    const int lc = l & 15;
    const int p = blockIdx.x * 256 + tid;  // one pixel per lane

    // ---- load f, moments via {0,+-1} structure of M (19 adds) ----
    float fv0 = f[0 * NPIX + p], fv1 = f[1 * NPIX + p], fv2 = f[2 * NPIX + p];
    float fv3 = f[3 * NPIX + p], fv4 = f[4 * NPIX + p], fv5 = f[5 * NPIX + p];
    float fv6 = f[6 * NPIX + p], fv7 = f[7 * NPIX + p], fv8 = f[8 * NPIX + p];
    float sa = fv5 + fv6, sb = fv7 + fv8, sc = fv5 - fv6, sd = fv7 - fv8;
    float sab = sa + sb;
    float m8 = sab, m6 = sa - sb, m4 = sc + sd, m7 = sc - sd;
    float p13 = fv1 + fv3, d13 = fv1 - fv3, p24 = fv2 + fv4, d24 = fv2 - fv4;
    float m0 = fv0 + p13 + p24 + sab;
    float m1 = d13 + m7;
    float m2 = d24 + m6;
    float m3 = p13 + sab;
    float m5 = p24 + sab;

    // ---- B1 frags: broadcast moments of pixels nb*16..nb*16+15 to all quads ----
    unsigned mp0 = pk2(m0, m1), mp1 = pk2(m2, m3), mp2 = pk2(m4, m5);
    const unsigned CONE = 0x00003F80u;  // (bf16 1.0 at k=6, 0 at k=7)
    bf16x8 B1[4];
    #pragma unroll
    for (int nb = 0; nb < 4; nb++) {
        int src = ((nb << 4) | lc) << 2;
        unsigned a = (unsigned)__builtin_amdgcn_ds_bpermute(src, (int)mp0);
        unsigned b = (unsigned)__builtin_amdgcn_ds_bpermute(src, (int)mp1);
        unsigned c = (unsigned)__builtin_amdgcn_ds_bpermute(src, (int)mp2);
        B1[nb] = mk8(a, b, c, CONE);  // only quad-0 rows (k=0..7) have nonzero A1
    }

    // ---- resident weights ----
    const bf16x8* wsv = (const bf16x8*)wsb;
    bf16x8 a2a = wsv[A2V + l], a2b = wsv[A2V + 64 + l];
    f32x4 c2iA = *(const f32x4*)(b2 + 8 * quad);       // bias of features 8q..8q+3
    f32x4 c2iB = *(const f32x4*)(b2 + 8 * quad + 4);   // features 8q+4..8q+7
    float b30 = wsf[B3TF + 0], b31 = wsf[B3TF + 1], b32 = wsf[B3TF + 2];
    f32x4 oinit;
    oinit[0] = (quad == 0) ? b30 : 0.f;
    oinit[1] = (quad == 0) ? b31 : 0.f;
    oinit[2] = (quad == 0) ? b32 : 0.f;
    oinit[3] = 0.f;
    const f32x4 zz = {0.f, 0.f, 0.f, 0.f};
    // even groups accumulate into oaccE (with b3t), odd groups into oaccO (zero-init)
    f32x4 oaccE[4] = {oinit, oinit, oinit, oinit};
    f32x4 oaccO[4] = {zz, zz, zz, zz};

    // current pair (g=0,1)
    bf16x8 a1aE = wsv[l],            a1bE = wsv[A1BV + l],            a3E = wsv[A3V + l];
    bf16x8 a1aO = wsv[64 + l],       a1bO = wsv[A1BV + 64 + l],       a3O = wsv[A3V + 64 + l];

    #pragma unroll 1
    for (int gp = 0; gp < 4; gp++) {
        const int gn = ((gp + 1) & 3) * 2;  // next pair base (gp=3 prefetch unused)
        bf16x8 na1aE = wsv[gn * 64 + l];
        bf16x8 na1bE = wsv[A1BV + gn * 64 + l];
        bf16x8 na3E  = wsv[A3V + gn * 64 + l];
        bf16x8 na1aO = wsv[(gn + 1) * 64 + l];
        bf16x8 na1bO = wsv[A1BV + (gn + 1) * 64 + l];
        bf16x8 na3O  = wsv[A3V + (gn + 1) * 64 + l];
        #pragma unroll
        for (int nb = 0; nb < 4; nb++) {
            // layer 1 (two independent groups)
            f32x4 c1aE = __builtin_amdgcn_mfma_f32_16x16x32_bf16(a1aE, B1[nb], zz, 0, 0, 0);
            f32x4 c1bE = __builtin_amdgcn_mfma_f32_16x16x32_bf16(a1bE, B1[nb], zz, 0, 0, 0);
            f32x4 c1aO = __builtin_amdgcn_mfma_f32_16x16x32_bf16(a1aO, B1[nb], zz, 0, 0, 0);
            f32x4 c1bO = __builtin_amdgcn_mfma_f32_16x16x32_bf16(a1bO, B1[nb], zz, 0, 0, 0);
            // lane-local C->B transform
            bf16x8 B2E = mk8(
                pk2(fmaxf(c1aE[0], 0.f), fmaxf(c1aE[1], 0.f)),
                pk2(fmaxf(c1aE[2], 0.f), fmaxf(c1aE[3], 0.f)),
                pk2(fmaxf(c1bE[0], 0.f), fmaxf(c1bE[1], 0.f)),
                pk2(fmaxf(c1bE[2], 0.f), fmaxf(c1bE[3], 0.f)));
            bf16x8 B2O = mk8(
                pk2(fmaxf(c1aO[0], 0.f), fmaxf(c1aO[1], 0.f)),
                pk2(fmaxf(c1aO[2], 0.f), fmaxf(c1aO[3], 0.f)),
                pk2(fmaxf(c1bO[0], 0.f), fmaxf(c1bO[1], 0.f)),
                pk2(fmaxf(c1bO[2], 0.f), fmaxf(c1bO[3], 0.f)));
            // layer 2 (bias via C-input)
            f32x4 c2aE = __builtin_amdgcn_mfma_f32_16x16x32_bf16(a2a, B2E, c2iA, 0, 0, 0);
            f32x4 c2bE = __builtin_amdgcn_mfma_f32_16x16x32_bf16(a2b, B2E, c2iB, 0, 0, 0);
            f32x4 c2aO = __builtin_amdgcn_mfma_f32_16x16x32_bf16(a2a, B2O, c2iA, 0, 0, 0);
            f32x4 c2bO = __builtin_amdgcn_mfma_f32_16x16x32_bf16(a2b, B2O, c2iB, 0, 0, 0);
            bf16x8 B3E = mk8(
                pk2(fmaxf(c2aE[0], 0.f), fmaxf(c2aE[1], 0.f)),
                pk2(fmaxf(c2aE[2], 0.f), fmaxf(c2aE[3], 0.f)),
                pk2(fmaxf(c2bE[0], 0.f), fmaxf(c2bE[1], 0.f)),
                pk2(fmaxf(c2bE[2], 0.f), fmaxf(c2bE[3], 0.f)));
            bf16x8 B3O = mk8(
                pk2(fmaxf(c2aO[0], 0.f), fmaxf(c2aO[1], 0.f)),
                pk2(fmaxf(c2aO[2], 0.f), fmaxf(c2aO[3], 0.f)),
                pk2(fmaxf(c2bO[0], 0.f), fmaxf(c2bO[1], 0.f)),
                pk2(fmaxf(c2bO[2], 0.f), fmaxf(c2bO[3], 0.f)));
            // layer 3: accumulate per-parity
            oaccE[nb] = __builtin_amdgcn_mfma_f32_16x16x32_bf16(a3E, B3E, oaccE[nb], 0, 0, 0);
            oaccO[nb] = __builtin_amdgcn_mfma_f32_16x16x32_bf16(a3O, B3O, oaccO[nb], 0, 0, 0);
        }
        a1aE = na1aE; a1bE = na1bE; a3E = na3E;
        a1aO = na1aO; a1bO = na1bO; a3O = na3O;
    }

    // ---- collect outputs: quad-0 lanes hold rows 0..3 (components) of cols 0..15 ----
    if (quad == 0) {
        #pragma unroll
        for (int nb = 0; nb < 4; nb++) {
            f32x4 ovs = oaccE[nb] + oaccO[nb];
            *(f32x4*)&oL[wv][nb * 16 + lc][0] = ovs;
        }
    }
    // wave-local LDS RAW: in-order per wave, lgkmcnt wait inserted by compiler; no barrier
    f32x4 ov = *(const f32x4*)&oL[wv][l][0];
    float o_[3] = {ov[0], ov[1], ov[2]};  // b3t already folded into oaccE init

    // ---- tau ----
    float tinv[3];
    #pragma unroll
    for (int i = 0; i < 3; i++) {
        float o = o_[i];
        float el = (o > 0.f) ? o : (__expf(o) - 1.f);
        tinv[i] = __builtin_amdgcn_rcpf(1.5f + el);
    }

    // ---- equilibrium (structured) ----
    float rho = m0;
    float ir = __builtin_amdgcn_rcpf(rho);
    float ux = m1 * ir, uy = m2 * ir;
    float usq = ux * ux + uy * uy;
    float base = 1.f - 1.5f * usq;
    float w0r = w[0] * rho, w1r = w[1] * rho, w5r = w[5] * rho;
    float feq0 = w0r * base;
    float ax = 4.5f * ux * ux + base, bx = 3.f * ux;
    float feq1 = w1r * (ax + bx), feq3 = w1r * (ax - bx);
    float ay = 4.5f * uy * uy + base, by = 3.f * uy;
    float feq2 = w1r * (ay + by), feq4 = w1r * (ay - by);
    float ss = ux + uy, as_ = 4.5f * ss * ss + base, bs = 3.f * ss;
    float feq5 = w5r * (as_ + bs), feq7 = w5r * (as_ - bs);
    float dd = uy - ux, ad = 4.5f * dd * dd + base, bd = 3.f * dd;
    float feq6 = w5r * (ad + bd), feq8 = w5r * (ad - bd);

    // meq = M @ feq (same 19-add structure)
    float ea = feq5 + feq6, eb = feq7 + feq8, ec = feq5 - feq6, ed = feq7 - feq8;
    float eab = ea + eb;
    float q8 = eab, q6 = ea - eb, q4 = ec + ed, q7 = ec - ed;
    float ep13 = feq1 + feq3, ed13 = feq1 - feq3, ep24 = feq2 + feq4, ed24 = feq2 - feq4;
    float q0 = feq0 + ep13 + ep24 + eab;
    float q1 = ed13 + q7, q2 = ed24 + q6, q3 = ep13 + eab, q5 = ep24 + eab;

    // relax
    float mp_[9];
    mp_[0] = m0 - (m0 - q0) * 1.25f;
    mp_[1] = m1 - (m1 - q1) * 1.25f;
    mp_[2] = m2 - (m2 - q2) * 1.25f;
    mp_[3] = m3 - (m3 - q3) * 1.25f;
    mp_[4] = m4 - (m4 - q4) * 1.25f;
    mp_[5] = m5 - (m5 - q5) * 1.25f;
    mp_[6] = m6 - (m6 - q6) * tinv[0];
    mp_[7] = m7 - (m7 - q7) * tinv[1];
    mp_[8] = m8 - (m8 - q8) * tinv[2];

    // out = Minv @ m_post (wave-uniform Minv -> scalar loads)
    #pragma unroll
    for (int q = 0; q < 9; q++) {
        float acc = Minv[q * 9 + 0] * mp_[0];
        #pragma unroll
        for (int pp = 1; pp < 9; pp++) acc = fmaf(Minv[q * 9 + pp], mp_[pp], acc);
        __builtin_nontemporal_store(acc, &out[q * NPIX + p]);
    }
}

extern "C" void kernel_launch(void* const* d_in, const int* in_sizes, int n_in,
                              void* d_out, int out_size, void* d_ws, size_t ws_size,
                              hipStream_t stream) {
    const float* f           = (const float*)d_in[0];
    const float* Minv        = (const float*)d_in[2];
    const float* actions     = (const float*)d_in[3];
    const float* inv_actions = (const float*)d_in[4];
    const float* w           = (const float*)d_in[6];
    const float* W1          = (const float*)d_in[7];
    const float* b1          = (const float*)d_in[8];
    const float* W2          = (const float*)d_in[9];
    const float* b2          = (const float*)d_in[10];
    const float* W3          = (const float*)d_in[11];
    const float* b3          = (const float*)d_in[12];
    float* outp = (float*)d_out;
    short* wsb = (short*)d_ws;
    float* wsf = (float*)d_ws;

    prep_kernel<<<53, 256, 0, stream>>>(actions, inv_actions, W1, b1, W2, W3, b3, wsb, wsf);
    lbm_kernel<<<NPIX / 256, 256, 0, stream>>>(f, Minv, w, b2, wsb, wsf, outp);
}